// Round 6
// baseline (928.009 us; speedup 1.0000x reference)
//
#include <hip/hip_runtime.h>
#include <math.h>

#define B   2
#define H   192
#define W   320
#define HW  (H * W)
#define BHW (B * HW)
#define CTX 195

// output offsets (in floats), concatenated in reference return order
#define OFS_CUR   0
#define OFS_REF0  (3 * BHW)
#define OFS_REF2  (6 * BHW)
#define OFS_CTX0  (9 * BHW)
#define OFS_CTX2  (9 * BHW + CTX * BHW)
#define OFS_OFF0  (9 * BHW + 2 * CTX * BHW)
#define OFS_OFF1  (OFS_OFF0 + 2 * BHW)

#define NCH   66
#define NGRP  3     // 198 channels (3 im + 195 ctx) = NCH * NGRP
#define TX    32
#define TY    8
#define NTX   (W / TX)          // 10
#define NTY   (H / TY)          // 24
#define NTILE (NTX * NTY * B)   // 480
#define NBLK  (NTILE * NGRP * 2) // 2880, divisible by 8

// LDS staging region: tile + 4-wide window + +/-MAXOFF flow bound
#define MAXOFF 20
#define RW   (TX + 4 + 2 * (MAXOFF + 1))   // 78 logical cols
#define RH   (TY + 4 + 2 * (MAXOFF + 1))   // 54 rows
#define RWP  80                            // padded stride (8B-aligned pairs)
#define RSZ  (RH * RW)                     // 4212 elements

typedef float f2v __attribute__((ext_vector_type(2)));

__device__ __forceinline__ int iclip(int v, int lo, int hi) {
    return v < lo ? lo : (v > hi ? hi : v);
}

// Forward splat: acc += -flow * d at 4 integer neighbors of (x+fx, y+fy); cnt += d.
__global__ __launch_bounds__(256) void splat_kernel(
    const float* __restrict__ flow0, const float* __restrict__ flow1,
    const float* __restrict__ dep0,  const float* __restrict__ dep1,
    float* __restrict__ out, float* __restrict__ cnt)
{
    int tid = blockIdx.x * blockDim.x + threadIdx.x;
    if (tid >= 2 * BHW) return;
    int s   = tid / BHW;
    int p   = tid - s * BHW;
    int b   = p / HW;
    int pix = p - b * HW;
    int y   = pix / W;
    int x   = pix - y * W;

    const float* flow = s ? flow1 : flow0;
    const float* dep  = s ? dep1  : dep0;
    float fx = flow[(b * 2 + 0) * HW + pix];
    float fy = flow[(b * 2 + 1) * HW + pix];
    float d  = dep[b * HW + pix];

    int xL = (int)floorf((float)x + fx);
    int yT = (int)floorf((float)y + fy);

    float* acc = out + (s ? OFS_OFF1 : OFS_OFF0) + b * 2 * HW;
    float* cn  = cnt + s * BHW + b * HW;

    float wx = -fx * d;
    float wy = -fy * d;
    #pragma unroll
    for (int dy = 0; dy < 2; dy++) {
        #pragma unroll
        for (int dx = 0; dx < 2; dx++) {
            int xi = xL + dx;
            int yi = yT + dy;
            if (xi >= 0 && xi < W && yi >= 0 && yi < H) {
                int q = yi * W + xi;
                atomicAdd(&acc[q],      wx);
                atomicAdd(&acc[HW + q], wy);
                atomicAdd(&cn[q],       d);
            }
        }
    }
}

// Normalize splat: off = acc / cnt where cnt > 0 else 0.
__global__ __launch_bounds__(256) void norm_kernel(
    float* __restrict__ out, const float* __restrict__ cnt)
{
    int tid = blockIdx.x * blockDim.x + threadIdx.x;
    if (tid >= 2 * BHW) return;
    int s   = tid / BHW;
    int p   = tid - s * BHW;
    int b   = p / HW;
    int pix = p - b * HW;

    float c = cnt[s * BHW + b * HW + pix];
    float* acc = out + (s ? OFS_OFF1 : OFS_OFF0) + b * 2 * HW;
    if (c > 0.0f) {
        acc[pix]      = acc[pix] / c;
        acc[HW + pix] = acc[HW + pix] / c;
    } else {
        acc[pix]      = 0.0f;
        acc[HW + pix] = 0.0f;
    }
}

// Per-pixel 4x4 adaptive filter bilinearly sampled at (x2+fi-1, y2+fj-1).
// Per-channel LDS halo staging (coalesced) + LDS gather (interior: merged 5x5;
// border: exact per-tap clamp); global fallback for |offset| > MAXOFF.
__global__ __launch_bounds__(256) void interp_kernel(
    const float* __restrict__ im0,   const float* __restrict__ im2,
    const float* __restrict__ ctx0,  const float* __restrict__ ctx2,
    const float* __restrict__ filt0, const float* __restrict__ filt1,
    float* __restrict__ out)
{
    __shared__ float lds[RH * RWP];   // 17280 B

    // XCD-aware swizzle: each XCD gets a contiguous chunk of work (NBLK % 8 == 0)
    int lin = blockIdx.x + NTILE * (blockIdx.y + NGRP * blockIdx.z);
    int newlin = (lin & 7) * (NBLK / 8) + (lin >> 3);
    int tile = newlin % NTILE;
    int rest = newlin / NTILE;
    int g = rest % NGRP;
    int s = rest / NGRP;
    int b  = tile / (NTX * NTY);
    int t2 = tile % (NTX * NTY);
    int tx0 = (t2 % NTX) * TX;
    int ty0 = (t2 / NTX) * TY;
    int x = tx0 + ((int)threadIdx.x % TX);
    int y = ty0 + ((int)threadIdx.x / TX);
    int pix = y * W + x;
    int rx0 = tx0 - (MAXOFF + 2);
    int ry0 = ty0 - (MAXOFF + 2);

    const float* off = out + (s ? OFS_OFF1 : OFS_OFF0) + b * 2 * HW;
    float ox = off[pix];
    float oy = off[HW + pix];
    float x2 = (float)x + ox;
    float y2 = (float)y + oy;

    bool valid = (x2 >= 0.0f) && (x2 <= (float)(W - 1)) &&
                 (y2 >= 0.0f) && (y2 <= (float)(H - 1));

    float xLf = floorf(x2), yTf = floorf(y2);
    float alpha = x2 - xLf, beta = y2 - yTf;
    int xL = (int)xLf, yT = (int)yTf;

    const float* filt = (s ? filt1 : filt0) + b * 16 * HW + pix;
    float fw[16];
    #pragma unroll
    for (int t = 0; t < 16; t++) fw[t] = filt[t * HW];

    float a00 = (1.0f - alpha) * (1.0f - beta);
    float a10 = alpha * (1.0f - beta);
    float a01 = (1.0f - alpha) * beta;
    float a11 = alpha * beta;

    bool interior = valid && (xL >= 1) && (xL <= W - 4) && (yT >= 1) && (yT <= H - 4);
    bool inreg    = valid && (xL - 1 >= rx0) && (xL + 4 <= rx0 + RW - 1) &&
                             (yT - 1 >= ry0) && (yT + 4 <= ry0 + RH - 1);

    // merged 5x5 stencil: correlation of F with the bilinear kernel
    float mw[5][5];
    #pragma unroll
    for (int r = 0; r < 5; r++) {
        #pragma unroll
        for (int c = 0; c < 5; c++) {
            float v = 0.0f;
            if (r < 4 && c < 4)   v += a00 * fw[r * 4 + c];
            if (r < 4 && c >= 1)  v += a10 * fw[r * 4 + c - 1];
            if (r >= 1 && c < 4)  v += a01 * fw[(r - 1) * 4 + c];
            if (r >= 1 && c >= 1) v += a11 * fw[(r - 1) * 4 + c - 1];
            mw[r][c] = v;
        }
    }

    // clamped tap indices (image coords) for the border path
    int xi[4], xi1[4], yi[4], yi1[4];
    #pragma unroll
    for (int f = 0; f < 4; f++) {
        int a = iclip(xL + f - 1, 0, W - 1);
        xi[f]  = a;
        xi1[f] = a + 1 > W - 1 ? W - 1 : a + 1;
        int bb = iclip(yT + f - 1, 0, H - 1);
        yi[f]  = bb;
        yi1[f] = bb + 1 > H - 1 ? H - 1 : bb + 1;
    }

    const float* imsrc  = s ? im2  : im0;
    const float* ctxsrc = s ? ctx2 : ctx0;
    float* oim  = out + (s ? OFS_REF2 : OFS_REF0) + b * 3 * HW + pix;
    float* octx = out + (s ? OFS_CTX2 : OFS_CTX0) + b * CTX * HW + pix;

    int c0 = g * NCH, c1 = c0 + NCH;

    for (int c = c0; c < c1; c++) {
        const float* plane = (c < 3) ? imsrc + (b * 3 + c) * HW
                                     : ctxsrc + (b * CTX + (c - 3)) * HW;

        __syncthreads();   // previous channel's readers done
        // stage halo region (coalesced float2 loads, zero-fill outside image)
        for (int i = (int)threadIdx.x; i < RSZ / 2; i += 256) {
            int l2 = i * 2;
            int lr = l2 / RW;
            int lc = l2 - lr * RW;
            int iy = ry0 + lr;
            int ix = rx0 + lc;
            float v0 = 0.0f, v1 = 0.0f;
            if ((unsigned)iy < (unsigned)H) {
                const float* rowp = plane + iy * W;
                if ((unsigned)ix < (unsigned)(W - 1)) {
                    f2v v = *(const f2v*)(rowp + ix);
                    v0 = v.x; v1 = v.y;
                } else {
                    if ((unsigned)ix < (unsigned)W)       v0 = rowp[ix];
                    if ((unsigned)(ix + 1) < (unsigned)W) v1 = rowp[ix + 1];
                }
            }
            *(f2v*)(&lds[lr * RWP + lc]) = (f2v){v0, v1};
        }
        __syncthreads();

        float accv = 0.0f;
        if (inreg) {
            if (interior) {
                int lb = (yT - 1 - ry0) * RWP + (xL - 1 - rx0);
                #pragma unroll
                for (int r = 0; r < 5; r++) {
                    const float* lp = &lds[lb + r * RWP];
                    accv = fmaf(mw[r][0], lp[0], accv);
                    accv = fmaf(mw[r][1], lp[1], accv);
                    accv = fmaf(mw[r][2], lp[2], accv);
                    accv = fmaf(mw[r][3], lp[3], accv);
                    accv = fmaf(mw[r][4], lp[4], accv);
                }
            } else {
                // exact border semantics from LDS (clamped coords are in-region)
                #pragma unroll
                for (int fj = 0; fj < 4; fj++) {
                    int rT = (yi[fj]  - ry0) * RWP - rx0;
                    int rB = (yi1[fj] - ry0) * RWP - rx0;
                    #pragma unroll
                    for (int fi = 0; fi < 4; fi++) {
                        float tl = lds[rT + xi[fi]];
                        float tr = lds[rT + xi1[fi]];
                        float bl = lds[rB + xi[fi]];
                        float br = lds[rB + xi1[fi]];
                        accv = fmaf(fw[fj * 4 + fi],
                                    a00 * tl + a10 * tr + a01 * bl + a11 * br, accv);
                    }
                }
            }
        } else if (valid) {
            // |offset| > MAXOFF: exact global fallback (rare)
            #pragma unroll
            for (int fj = 0; fj < 4; fj++) {
                const float* rT = plane + yi[fj]  * W;
                const float* rB = plane + yi1[fj] * W;
                #pragma unroll
                for (int fi = 0; fi < 4; fi++) {
                    float samp = a00 * rT[xi[fi]] + a10 * rT[xi1[fi]]
                               + a01 * rB[xi[fi]] + a11 * rB[xi1[fi]];
                    accv = fmaf(fw[fj * 4 + fi], samp, accv);
                }
            }
        }
        // invalid lanes: accv == 0
        if (c < 3) oim[c * HW] = accv;
        else       __builtin_nontemporal_store(accv, &octx[(c - 3) * HW]);
    }
}

__global__ __launch_bounds__(256) void cur_kernel(float* __restrict__ out)
{
    int i = blockIdx.x * blockDim.x + threadIdx.x;
    if (i < 3 * BHW)
        out[OFS_CUR + i] = 0.5f * (out[OFS_REF0 + i] + out[OFS_REF2 + i]);
}

extern "C" void kernel_launch(void* const* d_in, const int* in_sizes, int n_in,
                              void* d_out, int out_size, void* d_ws, size_t ws_size,
                              hipStream_t stream)
{
    const float* im0    = (const float*)d_in[0];
    const float* im2    = (const float*)d_in[1];
    const float* ctx0   = (const float*)d_in[2];
    const float* ctx2   = (const float*)d_in[3];
    const float* flow01 = (const float*)d_in[4];
    const float* flow10 = (const float*)d_in[5];
    const float* dep0   = (const float*)d_in[6];
    const float* dep1   = (const float*)d_in[7];
    const float* filt0  = (const float*)d_in[8];
    const float* filt1  = (const float*)d_in[9];

    float* out = (float*)d_out;
    float* cnt = (float*)d_ws;   // 2*BHW floats

    hipMemsetAsync(out + OFS_OFF0, 0, (size_t)(4 * BHW) * sizeof(float), stream);
    hipMemsetAsync(cnt, 0, (size_t)(2 * BHW) * sizeof(float), stream);

    dim3 blk(256);
    splat_kernel<<<dim3((2 * BHW + 255) / 256), blk, 0, stream>>>(
        flow01, flow10, dep0, dep1, out, cnt);
    norm_kernel<<<dim3((2 * BHW + 255) / 256), blk, 0, stream>>>(out, cnt);

    dim3 igrid(NTILE, NGRP, 2);
    interp_kernel<<<igrid, blk, 0, stream>>>(im0, im2, ctx0, ctx2, filt0, filt1, out);

    cur_kernel<<<dim3((3 * BHW + 255) / 256), blk, 0, stream>>>(out);
}

// Round 7
// 679.285 us; speedup vs baseline: 1.3662x; 1.3662x over previous
//
#include <hip/hip_runtime.h>
#include <math.h>

#define B   2
#define H   192
#define W   320
#define HW  (H * W)
#define BHW (B * HW)
#define CTX 195
#define CH  198   // 3 im + 195 ctx channels per side

// output offsets (in floats), concatenated in reference return order
#define OFS_CUR   0
#define OFS_REF0  (3 * BHW)
#define OFS_REF2  (6 * BHW)
#define OFS_CTX0  (9 * BHW)
#define OFS_CTX2  (9 * BHW + CTX * BHW)
#define OFS_OFF0  (9 * BHW + 2 * CTX * BHW)
#define OFS_OFF1  (OFS_OFF0 + 2 * BHW)

// transposed-path geometry
#define TSZ    ((size_t)2 * B * HW * CH)  // scratch floats for T
#define NXC    (W / 64)                   // 5 x-chunks of 64 px
#define NBLK_T (2 * B * H * NXC)          // 3840 interp blocks (div by 8)
#define NTB    (2 * B * (HW / 64))        // 3840 transpose blocks
#define LDSW   199                        // padded LDS row stride (odd -> conflict-free)

// fallback (R4) geometry
#define F_NCH   33
#define F_NGRP  6
#define F_TX    32
#define F_TY    8
#define F_NTX   (W / F_TX)
#define F_NTY   (H / F_TY)
#define F_NTILE (F_NTX * F_NTY * B)       // 480
#define F_NBLK  (F_NTILE * F_NGRP * 2)    // 5760

typedef float f2v __attribute__((ext_vector_type(2)));
typedef float f4a __attribute__((ext_vector_type(4), aligned(4)));

__device__ __forceinline__ int iclip(int v, int lo, int hi) {
    return v < lo ? lo : (v > hi ? hi : v);
}

// ---------------- splat / norm / cur (shared) ----------------

__global__ __launch_bounds__(256) void splat_kernel(
    const float* __restrict__ flow0, const float* __restrict__ flow1,
    const float* __restrict__ dep0,  const float* __restrict__ dep1,
    float* __restrict__ out, float* __restrict__ cnt)
{
    int tid = blockIdx.x * blockDim.x + threadIdx.x;
    if (tid >= 2 * BHW) return;
    int s   = tid / BHW;
    int p   = tid - s * BHW;
    int b   = p / HW;
    int pix = p - b * HW;
    int y   = pix / W;
    int x   = pix - y * W;

    const float* flow = s ? flow1 : flow0;
    const float* dep  = s ? dep1  : dep0;
    float fx = flow[(b * 2 + 0) * HW + pix];
    float fy = flow[(b * 2 + 1) * HW + pix];
    float d  = dep[b * HW + pix];

    int xL = (int)floorf((float)x + fx);
    int yT = (int)floorf((float)y + fy);

    float* acc = out + (s ? OFS_OFF1 : OFS_OFF0) + b * 2 * HW;
    float* cn  = cnt + s * BHW + b * HW;

    float wx = -fx * d;
    float wy = -fy * d;
    #pragma unroll
    for (int dy = 0; dy < 2; dy++) {
        #pragma unroll
        for (int dx = 0; dx < 2; dx++) {
            int xi = xL + dx;
            int yi = yT + dy;
            if (xi >= 0 && xi < W && yi >= 0 && yi < H) {
                int q = yi * W + xi;
                atomicAdd(&acc[q],      wx);
                atomicAdd(&acc[HW + q], wy);
                atomicAdd(&cn[q],       d);
            }
        }
    }
}

__global__ __launch_bounds__(256) void norm_kernel(
    float* __restrict__ out, const float* __restrict__ cnt)
{
    int tid = blockIdx.x * blockDim.x + threadIdx.x;
    if (tid >= 2 * BHW) return;
    int s   = tid / BHW;
    int p   = tid - s * BHW;
    int b   = p / HW;
    int pix = p - b * HW;

    float c = cnt[s * BHW + b * HW + pix];
    float* acc = out + (s ? OFS_OFF1 : OFS_OFF0) + b * 2 * HW;
    if (c > 0.0f) {
        acc[pix]      = acc[pix] / c;
        acc[HW + pix] = acc[HW + pix] / c;
    } else {
        acc[pix]      = 0.0f;
        acc[HW + pix] = 0.0f;
    }
}

__global__ __launch_bounds__(256) void cur_kernel(float* __restrict__ out)
{
    int i = blockIdx.x * blockDim.x + threadIdx.x;
    if (i < 3 * BHW)
        out[OFS_CUR + i] = 0.5f * (out[OFS_REF0 + i] + out[OFS_REF2 + i]);
}

// ---------------- transposed path ----------------

// T[((s*B+b)*HW + pix)*CH + c] = plane_c[pix]; coalesced both ways via LDS.
__global__ __launch_bounds__(256) void transpose_kernel(
    const float* __restrict__ im0,  const float* __restrict__ im2,
    const float* __restrict__ ctx0, const float* __restrict__ ctx2,
    float* __restrict__ T)
{
    __shared__ float lds[64 * LDSW];
    int lin   = blockIdx.x;             // (s, b, chunk)
    int chunk = lin % (HW / 64);
    int rest  = lin / (HW / 64);
    int b = rest % B;
    int s = rest / B;
    int pix0 = chunk * 64;

    const float* im  = s ? im2  : im0;
    const float* ctx = s ? ctx2 : ctx0;

    for (int j = (int)threadIdx.x; j < CH * 64; j += 256) {
        int c = j >> 6;        // channel
        int p = j & 63;        // pixel within chunk (consecutive lanes -> coalesced)
        const float* src = (c < 3) ? im + (b * 3 + c) * HW
                                   : ctx + (b * CTX + (c - 3)) * HW;
        lds[p * LDSW + c] = src[pix0 + p];
    }
    __syncthreads();
    float* Tb = T + ((size_t)((s * B + b) * HW + pix0)) * CH;
    for (int j = (int)threadIdx.x; j < CH * 64; j += 256) {
        int p = j / CH;
        int c = j - p * CH;    // consecutive lanes -> consecutive c -> coalesced
        Tb[(size_t)p * CH + c] = lds[p * LDSW + c];
    }
}

// One pixel per wave, lanes = channels (grp0: c=2*lane 0..127; grp1: c=128+2*lane).
// All geometry wave-uniform; gathers are contiguous 792B runs per position.
__global__ __launch_bounds__(256) void interp_t_kernel(
    const float* __restrict__ T,
    const float* __restrict__ filt0, const float* __restrict__ filt1,
    float* __restrict__ out)
{
    __shared__ float lds[64 * LDSW];

    int lin = blockIdx.x;
    int newlin = (lin & 7) * (NBLK_T / 8) + (lin >> 3);   // XCD swizzle
    int xs = newlin % NXC; int r1 = newlin / NXC;
    int y  = r1 % H;       int r2 = r1 / H;
    int b  = r2 % B;       int s  = r2 / B;
    int px0 = y * W + xs * 64;

    int wave = (int)threadIdx.x >> 6;
    int lane = (int)threadIdx.x & 63;
    int c0 = 2 * lane;                       // grp0 channels c0, c0+1
    int lcl = lane < 34 ? lane : 34;
    int c1 = 128 + 2 * lcl;                  // grp1 channels c1, c1+1 (lane>=35 dup)

    const float* off  = out + (s ? OFS_OFF1 : OFS_OFF0) + b * 2 * HW;
    const float* filt = (s ? filt1 : filt0) + b * 16 * HW;
    const float* Tb   = T + (size_t)(s * B + b) * HW * CH;

    for (int pp = wave * 16; pp < wave * 16 + 16; pp++) {
        int pix = px0 + pp;
        int x   = xs * 64 + pp;
        float ox = off[pix];
        float oy = off[HW + pix];
        float x2 = (float)x + ox;
        float y2 = (float)y + oy;
        bool valid = (x2 >= 0.0f) && (x2 <= (float)(W - 1)) &&
                     (y2 >= 0.0f) && (y2 <= (float)(H - 1));

        float a0x = 0.0f, a0y = 0.0f, a1x = 0.0f, a1y = 0.0f;

        if (valid) {
            float xLf = floorf(x2), yTf = floorf(y2);
            float alpha = x2 - xLf, beta = y2 - yTf;
            int xL = (int)xLf, yT = (int)yTf;

            float fw[16];
            #pragma unroll
            for (int t = 0; t < 16; t++) fw[t] = filt[t * HW + pix];

            float a00 = (1.0f - alpha) * (1.0f - beta);
            float a10 = alpha * (1.0f - beta);
            float a01 = (1.0f - alpha) * beta;
            float a11 = alpha * beta;

            bool interior = (xL >= 1) && (xL <= W - 4) && (yT >= 1) && (yT <= H - 4);
            if (interior) {
                float mw[5][5];
                #pragma unroll
                for (int r = 0; r < 5; r++) {
                    #pragma unroll
                    for (int c = 0; c < 5; c++) {
                        float v = 0.0f;
                        if (r < 4 && c < 4)   v += a00 * fw[r * 4 + c];
                        if (r < 4 && c >= 1)  v += a10 * fw[r * 4 + c - 1];
                        if (r >= 1 && c < 4)  v += a01 * fw[(r - 1) * 4 + c];
                        if (r >= 1 && c >= 1) v += a11 * fw[(r - 1) * 4 + c - 1];
                        mw[r][c] = v;
                    }
                }
                const float* basep = Tb + ((size_t)(yT - 1) * W + (xL - 1)) * CH;
                #pragma unroll
                for (int r = 0; r < 5; r++) {
                    #pragma unroll
                    for (int cc = 0; cc < 5; cc++) {
                        const float* ptr = basep + ((size_t)r * W + cc) * CH;
                        f2v v0 = *(const f2v*)(ptr + c0);
                        f2v v1 = *(const f2v*)(ptr + c1);
                        float wgt = mw[r][cc];
                        a0x = fmaf(wgt, v0.x, a0x);
                        a0y = fmaf(wgt, v0.y, a0y);
                        a1x = fmaf(wgt, v1.x, a1x);
                        a1y = fmaf(wgt, v1.y, a1y);
                    }
                }
            } else {
                // exact border semantics: per-tap independent clamping
                int xi[4], xi1[4], yi[4], yi1[4];
                #pragma unroll
                for (int f = 0; f < 4; f++) {
                    int a = iclip(xL + f - 1, 0, W - 1);
                    xi[f]  = a;
                    xi1[f] = a + 1 > W - 1 ? W - 1 : a + 1;
                    int bb = iclip(yT + f - 1, 0, H - 1);
                    yi[f]  = bb;
                    yi1[f] = bb + 1 > H - 1 ? H - 1 : bb + 1;
                }
                #pragma unroll
                for (int fj = 0; fj < 4; fj++) {
                    const float* rT = Tb + (size_t)yi[fj]  * W * CH;
                    const float* rB = Tb + (size_t)yi1[fj] * W * CH;
                    #pragma unroll
                    for (int fi = 0; fi < 4; fi++) {
                        const float* ptl = rT + (size_t)xi[fi]  * CH;
                        const float* ptr_ = rT + (size_t)xi1[fi] * CH;
                        const float* pbl = rB + (size_t)xi[fi]  * CH;
                        const float* pbr = rB + (size_t)xi1[fi] * CH;
                        f2v tl0 = *(const f2v*)(ptl + c0), tl1 = *(const f2v*)(ptl + c1);
                        f2v tr0 = *(const f2v*)(ptr_ + c0), tr1 = *(const f2v*)(ptr_ + c1);
                        f2v bl0 = *(const f2v*)(pbl + c0), bl1 = *(const f2v*)(pbl + c1);
                        f2v br0 = *(const f2v*)(pbr + c0), br1 = *(const f2v*)(pbr + c1);
                        float wgt = fw[fj * 4 + fi];
                        a0x = fmaf(wgt, a00*tl0.x + a10*tr0.x + a01*bl0.x + a11*br0.x, a0x);
                        a0y = fmaf(wgt, a00*tl0.y + a10*tr0.y + a01*bl0.y + a11*br0.y, a0y);
                        a1x = fmaf(wgt, a00*tl1.x + a10*tr1.x + a01*bl1.x + a11*br1.x, a1x);
                        a1y = fmaf(wgt, a00*tl1.y + a10*tr1.y + a01*bl1.y + a11*br1.y, a1y);
                    }
                }
            }
        }

        int lb = pp * LDSW;
        lds[lb + c0]     = a0x;
        lds[lb + c0 + 1] = a0y;
        if (lane < 35) {
            lds[lb + c1]     = a1x;
            lds[lb + c1 + 1] = a1y;
        }
    }

    __syncthreads();
    // coalesced plane writes: fixed c, 64 consecutive pixels
    for (int j = (int)threadIdx.x; j < CH * 64; j += 256) {
        int c = j >> 6;
        int p = j & 63;
        float v = lds[p * LDSW + c];
        if (c < 3)
            out[(s ? OFS_REF2 : OFS_REF0) + (b * 3 + c) * HW + px0 + p] = v;
        else
            __builtin_nontemporal_store(
                v, &out[(s ? OFS_CTX2 : OFS_CTX0) + (b * CTX + (c - 3)) * HW + px0 + p]);
    }
}

// ---------------- fallback path (R4, proven 712us) ----------------

#define VBODY(PLANE, STORE)                                            \
    {                                                                  \
        const float* p0 = (PLANE) + base;                              \
        float acc = 0.0f;                                              \
        _Pragma("unroll")                                              \
        for (int r = 0; r < 5; r++) {                                  \
            const float* row = p0 + r * W;                             \
            f4a v0 = *(const f4a*)row;                                 \
            float v4 = row[4];                                         \
            acc = fmaf(mw[r][0], v0.x, acc);                           \
            acc = fmaf(mw[r][1], v0.y, acc);                           \
            acc = fmaf(mw[r][2], v0.z, acc);                           \
            acc = fmaf(mw[r][3], v0.w, acc);                           \
            acc = fmaf(mw[r][4], v4,   acc);                           \
        }                                                              \
        STORE;                                                         \
    }

#define BBODY(PLANE, STORE)                                            \
    {                                                                  \
        const float* plane = (PLANE);                                  \
        float acc = 0.0f;                                              \
        _Pragma("unroll")                                              \
        for (int fj = 0; fj < 4; fj++) {                               \
            const float* rT = plane + yi[fj]  * W;                     \
            const float* rB = plane + yi1[fj] * W;                     \
            _Pragma("unroll")                                          \
            for (int fi = 0; fi < 4; fi++) {                           \
                float samp = a00 * rT[xi[fi]] + a10 * rT[xi1[fi]]      \
                           + a01 * rB[xi[fi]] + a11 * rB[xi1[fi]];     \
                acc = fmaf(fw[fj * 4 + fi], samp, acc);                \
            }                                                          \
        }                                                              \
        STORE;                                                         \
    }

__global__ __launch_bounds__(256) void interp_f_kernel(
    const float* __restrict__ im0,   const float* __restrict__ im2,
    const float* __restrict__ ctx0,  const float* __restrict__ ctx2,
    const float* __restrict__ filt0, const float* __restrict__ filt1,
    float* __restrict__ out)
{
    int lin = blockIdx.x + F_NTILE * (blockIdx.y + F_NGRP * blockIdx.z);
    int newlin = (lin & 7) * (F_NBLK / 8) + (lin >> 3);
    int tile = newlin % F_NTILE;
    int rest = newlin / F_NTILE;
    int g = rest % F_NGRP;
    int s = rest / F_NGRP;
    int b  = tile / (F_NTX * F_NTY);
    int t2 = tile % (F_NTX * F_NTY);
    int x = (t2 % F_NTX) * F_TX + ((int)threadIdx.x % F_TX);
    int y = (t2 / F_NTX) * F_TY + ((int)threadIdx.x / F_TX);
    int pix = y * W + x;

    const float* off = out + (s ? OFS_OFF1 : OFS_OFF0) + b * 2 * HW;
    float ox = off[pix];
    float oy = off[HW + pix];
    float x2 = (float)x + ox;
    float y2 = (float)y + oy;

    bool valid = (x2 >= 0.0f) && (x2 <= (float)(W - 1)) &&
                 (y2 >= 0.0f) && (y2 <= (float)(H - 1));

    const float* imsrc  = s ? im2  : im0;
    const float* ctxsrc = s ? ctx2 : ctx0;
    float* oim  = out + (s ? OFS_REF2 : OFS_REF0) + b * 3 * HW + pix;
    float* octx = out + (s ? OFS_CTX2 : OFS_CTX0) + b * CTX * HW + pix;

    int c0 = g * F_NCH, c1 = c0 + F_NCH;
    int imEnd  = c1 < 3 ? c1 : 3;
    int ctxBeg = c0 > 3 ? c0 : 3;

    if (!valid) {
        for (int c = c0; c < imEnd; c++) oim[c * HW] = 0.0f;
        for (int c = ctxBeg; c < c1; c++)
            __builtin_nontemporal_store(0.0f, &octx[(c - 3) * HW]);
        return;
    }

    float xLf = floorf(x2), yTf = floorf(y2);
    float alpha = x2 - xLf, beta = y2 - yTf;
    int xL = (int)xLf, yT = (int)yTf;

    const float* filt = (s ? filt1 : filt0) + b * 16 * HW + pix;
    float fw[16];
    #pragma unroll
    for (int t = 0; t < 16; t++) fw[t] = filt[t * HW];

    float a00 = (1.0f - alpha) * (1.0f - beta);
    float a10 = alpha * (1.0f - beta);
    float a01 = (1.0f - alpha) * beta;
    float a11 = alpha * beta;

    bool interior = (xL >= 1) && (xL <= W - 4) && (yT >= 1) && (yT <= H - 4);

    if (interior) {
        float mw[5][5];
        #pragma unroll
        for (int r = 0; r < 5; r++) {
            #pragma unroll
            for (int c = 0; c < 5; c++) {
                float v = 0.0f;
                if (r < 4 && c < 4)   v += a00 * fw[r * 4 + c];
                if (r < 4 && c >= 1)  v += a10 * fw[r * 4 + c - 1];
                if (r >= 1 && c < 4)  v += a01 * fw[(r - 1) * 4 + c];
                if (r >= 1 && c >= 1) v += a11 * fw[(r - 1) * 4 + c - 1];
                mw[r][c] = v;
            }
        }
        int base = (yT - 1) * W + (xL - 1);
        for (int c = c0; c < imEnd; c++)
            VBODY(imsrc + (b * 3 + c) * HW, oim[c * HW] = acc)
        #pragma unroll 2
        for (int c = ctxBeg; c < c1; c++)
            VBODY(ctxsrc + (b * CTX + (c - 3)) * HW,
                  __builtin_nontemporal_store(acc, &octx[(c - 3) * HW]))
    } else {
        int xi[4], xi1[4], yi[4], yi1[4];
        #pragma unroll
        for (int f = 0; f < 4; f++) {
            int a = iclip(xL + f - 1, 0, W - 1);
            xi[f]  = a;
            xi1[f] = a + 1 > W - 1 ? W - 1 : a + 1;
            int bb = iclip(yT + f - 1, 0, H - 1);
            yi[f]  = bb;
            yi1[f] = bb + 1 > H - 1 ? H - 1 : bb + 1;
        }
        for (int c = c0; c < imEnd; c++)
            BBODY(imsrc + (b * 3 + c) * HW, oim[c * HW] = acc)
        for (int c = ctxBeg; c < c1; c++)
            BBODY(ctxsrc + (b * CTX + (c - 3)) * HW,
                  __builtin_nontemporal_store(acc, &octx[(c - 3) * HW]))
    }
}

// ---------------- launch ----------------

extern "C" void kernel_launch(void* const* d_in, const int* in_sizes, int n_in,
                              void* d_out, int out_size, void* d_ws, size_t ws_size,
                              hipStream_t stream)
{
    const float* im0    = (const float*)d_in[0];
    const float* im2    = (const float*)d_in[1];
    const float* ctx0   = (const float*)d_in[2];
    const float* ctx2   = (const float*)d_in[3];
    const float* flow01 = (const float*)d_in[4];
    const float* flow10 = (const float*)d_in[5];
    const float* dep0   = (const float*)d_in[6];
    const float* dep1   = (const float*)d_in[7];
    const float* filt0  = (const float*)d_in[8];
    const float* filt1  = (const float*)d_in[9];

    float* out = (float*)d_out;

    size_t need = (TSZ + (size_t)2 * BHW) * sizeof(float);
    bool use_t = ws_size >= need;

    float* T   = (float*)d_ws;
    float* cnt = use_t ? ((float*)d_ws + TSZ) : (float*)d_ws;

    hipMemsetAsync(out + OFS_OFF0, 0, (size_t)(4 * BHW) * sizeof(float), stream);
    hipMemsetAsync(cnt, 0, (size_t)(2 * BHW) * sizeof(float), stream);

    dim3 blk(256);
    splat_kernel<<<dim3((2 * BHW + 255) / 256), blk, 0, stream>>>(
        flow01, flow10, dep0, dep1, out, cnt);
    norm_kernel<<<dim3((2 * BHW + 255) / 256), blk, 0, stream>>>(out, cnt);

    if (use_t) {
        transpose_kernel<<<dim3(NTB), blk, 0, stream>>>(im0, im2, ctx0, ctx2, T);
        interp_t_kernel<<<dim3(NBLK_T), blk, 0, stream>>>(T, filt0, filt1, out);
    } else {
        dim3 igrid(F_NTILE, F_NGRP, 2);
        interp_f_kernel<<<igrid, blk, 0, stream>>>(
            im0, im2, ctx0, ctx2, filt0, filt1, out);
    }

    cur_kernel<<<dim3((3 * BHW + 255) / 256), blk, 0, stream>>>(out);
}

// Round 9
// 543.719 us; speedup vs baseline: 1.7068x; 1.2493x over previous
//
#include <hip/hip_runtime.h>
#include <math.h>

#define B   2
#define H   192
#define W   320
#define HW  (H * W)
#define BHW (B * HW)
#define CTX 195
#define CH  198   // 3 im + 195 ctx channels per side

// output offsets (in floats), concatenated in reference return order
#define OFS_CUR   0
#define OFS_REF0  (3 * BHW)
#define OFS_REF2  (6 * BHW)
#define OFS_CTX0  (9 * BHW)
#define OFS_CTX2  (9 * BHW + CTX * BHW)
#define OFS_OFF0  (9 * BHW + 2 * CTX * BHW)
#define OFS_OFF1  (OFS_OFF0 + 2 * BHW)

// transposed-path geometry
#define TSZ    ((size_t)2 * B * HW * CH)  // scratch floats for T
#define NTB    (2 * B * (HW / 64))        // 3840 transpose blocks
#define LDSW   199                        // transpose LDS row stride (odd)
#define NPXB   32                         // pixels per interp block
#define NTHR   512                        // interp block threads (8 waves)
#define NCHK   (HW / NPXB)                // 1920 chunks per (s,b) image
#define NBLK2  (2 * B * NCHK)             // 7680 interp blocks, div by 8

// fallback (R4) geometry
#define F_NCH   33
#define F_NGRP  6
#define F_TX    32
#define F_TY    8
#define F_NTX   (W / F_TX)
#define F_NTY   (H / F_TY)
#define F_NTILE (F_NTX * F_NTY * B)       // 480
#define F_NBLK  (F_NTILE * F_NGRP * 2)    // 5760

typedef float f2v __attribute__((ext_vector_type(2)));
typedef float f4a __attribute__((ext_vector_type(4), aligned(4)));

__device__ __forceinline__ int iclip(int v, int lo, int hi) {
    return v < lo ? lo : (v > hi ? hi : v);
}

// ---------------- splat / norm / cur ----------------

__global__ __launch_bounds__(256) void splat_kernel(
    const float* __restrict__ flow0, const float* __restrict__ flow1,
    const float* __restrict__ dep0,  const float* __restrict__ dep1,
    float* __restrict__ out, float* __restrict__ cnt)
{
    int tid = blockIdx.x * blockDim.x + threadIdx.x;
    if (tid >= 2 * BHW) return;
    int s   = tid / BHW;
    int p   = tid - s * BHW;
    int b   = p / HW;
    int pix = p - b * HW;
    int y   = pix / W;
    int x   = pix - y * W;

    const float* flow = s ? flow1 : flow0;
    const float* dep  = s ? dep1  : dep0;
    float fx = flow[(b * 2 + 0) * HW + pix];
    float fy = flow[(b * 2 + 1) * HW + pix];
    float d  = dep[b * HW + pix];

    int xL = (int)floorf((float)x + fx);
    int yT = (int)floorf((float)y + fy);

    float* acc = out + (s ? OFS_OFF1 : OFS_OFF0) + b * 2 * HW;
    float* cn  = cnt + s * BHW + b * HW;

    float wx = -fx * d;
    float wy = -fy * d;
    #pragma unroll
    for (int dy = 0; dy < 2; dy++) {
        #pragma unroll
        for (int dx = 0; dx < 2; dx++) {
            int xi = xL + dx;
            int yi = yT + dy;
            if (xi >= 0 && xi < W && yi >= 0 && yi < H) {
                int q = yi * W + xi;
                atomicAdd(&acc[q],      wx);
                atomicAdd(&acc[HW + q], wy);
                atomicAdd(&cn[q],       d);
            }
        }
    }
}

__global__ __launch_bounds__(256) void norm_kernel(
    float* __restrict__ out, const float* __restrict__ cnt)
{
    int tid = blockIdx.x * blockDim.x + threadIdx.x;
    if (tid >= 2 * BHW) return;
    int s   = tid / BHW;
    int p   = tid - s * BHW;
    int b   = p / HW;
    int pix = p - b * HW;

    float c = cnt[s * BHW + b * HW + pix];
    float* acc = out + (s ? OFS_OFF1 : OFS_OFF0) + b * 2 * HW;
    if (c > 0.0f) {
        acc[pix]      = acc[pix] / c;
        acc[HW + pix] = acc[HW + pix] / c;
    } else {
        acc[pix]      = 0.0f;
        acc[HW + pix] = 0.0f;
    }
}

__global__ __launch_bounds__(256) void cur_kernel(float* __restrict__ out)
{
    int i = blockIdx.x * blockDim.x + threadIdx.x;
    if (i < 3 * BHW)
        out[OFS_CUR + i] = 0.5f * (out[OFS_REF0 + i] + out[OFS_REF2 + i]);
}

// ---------------- transposed path ----------------

// T[((s*B+b)*HW + pix)*CH + c] = plane_c[pix]; coalesced both ways via LDS.
__global__ __launch_bounds__(256) void transpose_kernel(
    const float* __restrict__ im0,  const float* __restrict__ im2,
    const float* __restrict__ ctx0, const float* __restrict__ ctx2,
    float* __restrict__ T)
{
    __shared__ float lds[64 * LDSW];
    int lin   = blockIdx.x;
    int chunk = lin % (HW / 64);
    int rest  = lin / (HW / 64);
    int b = rest % B;
    int s = rest / B;
    int pix0 = chunk * 64;

    const float* im  = s ? im2  : im0;
    const float* ctx = s ? ctx2 : ctx0;

    for (int j = (int)threadIdx.x; j < CH * 64; j += 256) {
        int c = j >> 6;
        int p = j & 63;
        const float* src = (c < 3) ? im + (b * 3 + c) * HW
                                   : ctx + (b * CTX + (c - 3)) * HW;
        lds[p * LDSW + c] = src[pix0 + p];
    }
    __syncthreads();
    float* Tb = T + ((size_t)((s * B + b) * HW + pix0)) * CH;
    for (int j = (int)threadIdx.x; j < CH * 64; j += 256) {
        int p = j / CH;
        int c = j - p * CH;
        Tb[(size_t)p * CH + c] = lds[p * LDSW + c];
    }
}

// 8 waves x 4 px each; lanes = channel quads (c = 4*lane, 50 active).
// Cooperative setup: filt/geometry/merged-5x5 computed once per pixel into LDS.
__global__ __launch_bounds__(NTHR) void interp_t_kernel(
    const float* __restrict__ T,
    const float* __restrict__ filt0, const float* __restrict__ filt1,
    float* __restrict__ out)
{
    __shared__ float fwl[NPXB * 17];    // [p][tap], stride 17
    __shared__ float mwl[NPXB * 25];    // [p][r*5+c]
    __shared__ float geof[NPXB * 6];    // a00,a10,a01,a11
    __shared__ int   geoi[NPXB * 4];    // flag(0 inv,1 int,2 bord), xL, yT
    __shared__ float outb[NPXB * 199];  // [p][c], stride 199 (odd)

    int lin = blockIdx.x;
    int newlin = (lin & 7) * (NBLK2 / 8) + (lin >> 3);   // XCD swizzle
    int chunk = newlin % NCHK;
    int rest  = newlin / NCHK;
    int b = rest % B;
    int s = rest / B;
    int px0 = chunk * NPXB;      // 32 consecutive px, within one row (320%32==0)
    int y0  = px0 / W;
    int x0  = px0 - y0 * W;

    const float* off  = out + (s ? OFS_OFF1 : OFS_OFF0) + b * 2 * HW;
    const float* filt = (s ? filt1 : filt0) + b * 16 * HW;
    const float* Tb   = T + (size_t)(s * B + b) * HW * CH;

    int t = (int)threadIdx.x;

    // cooperative filt load (coalesced: consecutive lanes -> consecutive px)
    for (int idx = t; idx < 16 * NPXB; idx += NTHR) {
        int tap = idx >> 5, p = idx & 31;
        fwl[p * 17 + tap] = filt[tap * HW + px0 + p];
    }
    // per-pixel geometry
    if (t < NPXB) {
        int p = t;
        float ox = off[px0 + p];
        float oy = off[HW + px0 + p];
        float x2 = (float)(x0 + p) + ox;
        float y2 = (float)y0 + oy;
        bool valid = (x2 >= 0.0f) && (x2 <= (float)(W - 1)) &&
                     (y2 >= 0.0f) && (y2 <= (float)(H - 1));
        float xLf = floorf(x2), yTf = floorf(y2);
        float al = x2 - xLf, be = y2 - yTf;
        int xL = (int)xLf, yT = (int)yTf;
        bool interior = valid && (xL >= 1) && (xL <= W - 4) &&
                                 (yT >= 1) && (yT <= H - 4);
        geof[p * 6 + 0] = valid ? (1.0f - al) * (1.0f - be) : 0.0f;
        geof[p * 6 + 1] = valid ? al * (1.0f - be) : 0.0f;
        geof[p * 6 + 2] = valid ? (1.0f - al) * be : 0.0f;
        geof[p * 6 + 3] = valid ? al * be : 0.0f;
        geoi[p * 4 + 0] = valid ? (interior ? 1 : 2) : 0;
        geoi[p * 4 + 1] = xL;
        geoi[p * 4 + 2] = yT;
    }
    __syncthreads();
    // merged 5x5 weights, computed once per pixel (parallel over (p, rc))
    for (int idx = t; idx < 25 * NPXB; idx += NTHR) {
        int p = idx / 25, rc = idx - p * 25;
        int r = rc / 5, c = rc - r * 5;
        float a00 = geof[p * 6 + 0], a10 = geof[p * 6 + 1];
        float a01 = geof[p * 6 + 2], a11 = geof[p * 6 + 3];
        const float* fw = &fwl[p * 17];
        float v = 0.0f;
        if (r < 4 && c < 4)   v += a00 * fw[r * 4 + c];
        if (r < 4 && c >= 1)  v += a10 * fw[r * 4 + c - 1];
        if (r >= 1 && c < 4)  v += a01 * fw[(r - 1) * 4 + c];
        if (r >= 1 && c >= 1) v += a11 * fw[(r - 1) * 4 + c - 1];
        mwl[p * 25 + rc] = v;
    }
    __syncthreads();

    int wave = t >> 6, lane = t & 63;        // wave in [0,8)
    int lcl = lane < 49 ? lane : 49;
    int cc0 = 4 * lcl;                       // channels cc0..cc0+3
    int nwr = lane < 49 ? 4 : (lane == 49 ? 2 : 0);

    #pragma unroll
    for (int pi = 0; pi < 4; pi++) {
        int p = wave * 4 + pi;               // 8 waves x 4 px = 32 px
        int flag = geoi[p * 4];
        float acc0 = 0.0f, acc1 = 0.0f, acc2 = 0.0f, acc3 = 0.0f;
        if (flag == 1) {
            int xL = geoi[p * 4 + 1], yT = geoi[p * 4 + 2];
            const float* basep = Tb + ((size_t)(yT - 1) * W + (xL - 1)) * CH + cc0;
            #pragma unroll
            for (int r = 0; r < 5; r++) {
                #pragma unroll
                for (int cc = 0; cc < 5; cc++) {
                    f4a v = *(const f4a*)(basep + ((size_t)r * W + cc) * CH);
                    float wgt = mwl[p * 25 + r * 5 + cc];
                    acc0 = fmaf(wgt, v.x, acc0);
                    acc1 = fmaf(wgt, v.y, acc1);
                    acc2 = fmaf(wgt, v.z, acc2);
                    acc3 = fmaf(wgt, v.w, acc3);
                }
            }
        } else if (flag == 2) {
            // exact border semantics: per-tap independent clamping
            int xL = geoi[p * 4 + 1], yT = geoi[p * 4 + 2];
            float a00 = geof[p * 6 + 0], a10 = geof[p * 6 + 1];
            float a01 = geof[p * 6 + 2], a11 = geof[p * 6 + 3];
            int xi[4], xi1[4], yi[4], yi1[4];
            #pragma unroll
            for (int f = 0; f < 4; f++) {
                int a = iclip(xL + f - 1, 0, W - 1);
                xi[f]  = a;
                xi1[f] = a + 1 > W - 1 ? W - 1 : a + 1;
                int bb = iclip(yT + f - 1, 0, H - 1);
                yi[f]  = bb;
                yi1[f] = bb + 1 > H - 1 ? H - 1 : bb + 1;
            }
            #pragma unroll
            for (int fj = 0; fj < 4; fj++) {
                #pragma unroll
                for (int fi = 0; fi < 4; fi++) {
                    const float* ptl = Tb + ((size_t)yi[fj]  * W + xi[fi])  * CH + cc0;
                    const float* ptr_ = Tb + ((size_t)yi[fj]  * W + xi1[fi]) * CH + cc0;
                    const float* pbl = Tb + ((size_t)yi1[fj] * W + xi[fi])  * CH + cc0;
                    const float* pbr = Tb + ((size_t)yi1[fj] * W + xi1[fi]) * CH + cc0;
                    f4a tl = *(const f4a*)ptl;
                    f4a tr = *(const f4a*)ptr_;
                    f4a bl = *(const f4a*)pbl;
                    f4a br = *(const f4a*)pbr;
                    float wgt = fwl[p * 17 + fj * 4 + fi];
                    acc0 = fmaf(wgt, a00*tl.x + a10*tr.x + a01*bl.x + a11*br.x, acc0);
                    acc1 = fmaf(wgt, a00*tl.y + a10*tr.y + a01*bl.y + a11*br.y, acc1);
                    acc2 = fmaf(wgt, a00*tl.z + a10*tr.z + a01*bl.z + a11*br.z, acc2);
                    acc3 = fmaf(wgt, a00*tl.w + a10*tr.w + a01*bl.w + a11*br.w, acc3);
                }
            }
        }
        float* ob = &outb[p * 199 + cc0];
        if (nwr == 4) { ob[0] = acc0; ob[1] = acc1; ob[2] = acc2; ob[3] = acc3; }
        else if (nwr == 2) { ob[0] = acc0; ob[1] = acc1; }
    }

    __syncthreads();
    // coalesced plane writes: fixed c, 32 consecutive pixels
    for (int idx = t; idx < CH * NPXB; idx += NTHR) {
        int c = idx >> 5;
        int p = idx & 31;
        float v = outb[p * 199 + c];
        if (c < 3)
            out[(s ? OFS_REF2 : OFS_REF0) + (b * 3 + c) * HW + px0 + p] = v;
        else
            __builtin_nontemporal_store(
                v, &out[(s ? OFS_CTX2 : OFS_CTX0) + (b * CTX + (c - 3)) * HW + px0 + p]);
    }
}

// ---------------- fallback path (R4, proven 712us) ----------------

#define VBODY(PLANE, STORE)                                            \
    {                                                                  \
        const float* p0 = (PLANE) + base;                              \
        float acc = 0.0f;                                              \
        _Pragma("unroll")                                              \
        for (int r = 0; r < 5; r++) {                                  \
            const float* row = p0 + r * W;                             \
            f4a v0 = *(const f4a*)row;                                 \
            float v4 = row[4];                                         \
            acc = fmaf(mw[r][0], v0.x, acc);                           \
            acc = fmaf(mw[r][1], v0.y, acc);                           \
            acc = fmaf(mw[r][2], v0.z, acc);                           \
            acc = fmaf(mw[r][3], v0.w, acc);                           \
            acc = fmaf(mw[r][4], v4,   acc);                           \
        }                                                              \
        STORE;                                                         \
    }

#define BBODY(PLANE, STORE)                                            \
    {                                                                  \
        const float* plane = (PLANE);                                  \
        float acc = 0.0f;                                              \
        _Pragma("unroll")                                              \
        for (int fj = 0; fj < 4; fj++) {                               \
            const float* rT = plane + yi[fj]  * W;                     \
            const float* rB = plane + yi1[fj] * W;                     \
            _Pragma("unroll")                                          \
            for (int fi = 0; fi < 4; fi++) {                           \
                float samp = a00 * rT[xi[fi]] + a10 * rT[xi1[fi]]      \
                           + a01 * rB[xi[fi]] + a11 * rB[xi1[fi]];     \
                acc = fmaf(fw[fj * 4 + fi], samp, acc);                \
            }                                                          \
        }                                                              \
        STORE;                                                         \
    }

__global__ __launch_bounds__(256) void interp_f_kernel(
    const float* __restrict__ im0,   const float* __restrict__ im2,
    const float* __restrict__ ctx0,  const float* __restrict__ ctx2,
    const float* __restrict__ filt0, const float* __restrict__ filt1,
    float* __restrict__ out)
{
    int lin = blockIdx.x + F_NTILE * (blockIdx.y + F_NGRP * blockIdx.z);
    int newlin = (lin & 7) * (F_NBLK / 8) + (lin >> 3);
    int tile = newlin % F_NTILE;
    int rest = newlin / F_NTILE;
    int g = rest % F_NGRP;
    int s = rest / F_NGRP;
    int b  = tile / (F_NTX * F_NTY);
    int t2 = tile % (F_NTX * F_NTY);
    int x = (t2 % F_NTX) * F_TX + ((int)threadIdx.x % F_TX);
    int y = (t2 / F_NTX) * F_TY + ((int)threadIdx.x / F_TX);
    int pix = y * W + x;

    const float* off = out + (s ? OFS_OFF1 : OFS_OFF0) + b * 2 * HW;
    float ox = off[pix];
    float oy = off[HW + pix];
    float x2 = (float)x + ox;
    float y2 = (float)y + oy;

    bool valid = (x2 >= 0.0f) && (x2 <= (float)(W - 1)) &&
                 (y2 >= 0.0f) && (y2 <= (float)(H - 1));

    const float* imsrc  = s ? im2  : im0;
    const float* ctxsrc = s ? ctx2 : ctx0;
    float* oim  = out + (s ? OFS_REF2 : OFS_REF0) + b * 3 * HW + pix;
    float* octx = out + (s ? OFS_CTX2 : OFS_CTX0) + b * CTX * HW + pix;

    int c0 = g * F_NCH, c1 = c0 + F_NCH;
    int imEnd  = c1 < 3 ? c1 : 3;
    int ctxBeg = c0 > 3 ? c0 : 3;

    if (!valid) {
        for (int c = c0; c < imEnd; c++) oim[c * HW] = 0.0f;
        for (int c = ctxBeg; c < c1; c++)
            __builtin_nontemporal_store(0.0f, &octx[(c - 3) * HW]);
        return;
    }

    float xLf = floorf(x2), yTf = floorf(y2);
    float alpha = x2 - xLf, beta = y2 - yTf;
    int xL = (int)xLf, yT = (int)yTf;

    const float* filt = (s ? filt1 : filt0) + b * 16 * HW + pix;
    float fw[16];
    #pragma unroll
    for (int t = 0; t < 16; t++) fw[t] = filt[t * HW];

    float a00 = (1.0f - alpha) * (1.0f - beta);
    float a10 = alpha * (1.0f - beta);
    float a01 = (1.0f - alpha) * beta;
    float a11 = alpha * beta;

    bool interior = (xL >= 1) && (xL <= W - 4) && (yT >= 1) && (yT <= H - 4);

    if (interior) {
        float mw[5][5];
        #pragma unroll
        for (int r = 0; r < 5; r++) {
            #pragma unroll
            for (int c = 0; c < 5; c++) {
                float v = 0.0f;
                if (r < 4 && c < 4)   v += a00 * fw[r * 4 + c];
                if (r < 4 && c >= 1)  v += a10 * fw[r * 4 + c - 1];
                if (r >= 1 && c < 4)  v += a01 * fw[(r - 1) * 4 + c];
                if (r >= 1 && c >= 1) v += a11 * fw[(r - 1) * 4 + c - 1];
                mw[r][c] = v;
            }
        }
        int base = (yT - 1) * W + (xL - 1);
        for (int c = c0; c < imEnd; c++)
            VBODY(imsrc + (b * 3 + c) * HW, oim[c * HW] = acc)
        #pragma unroll 2
        for (int c = ctxBeg; c < c1; c++)
            VBODY(ctxsrc + (b * CTX + (c - 3)) * HW,
                  __builtin_nontemporal_store(acc, &octx[(c - 3) * HW]))
    } else {
        int xi[4], xi1[4], yi[4], yi1[4];
        #pragma unroll
        for (int f = 0; f < 4; f++) {
            int a = iclip(xL + f - 1, 0, W - 1);
            xi[f]  = a;
            xi1[f] = a + 1 > W - 1 ? W - 1 : a + 1;
            int bb = iclip(yT + f - 1, 0, H - 1);
            yi[f]  = bb;
            yi1[f] = bb + 1 > H - 1 ? H - 1 : bb + 1;
        }
        for (int c = c0; c < imEnd; c++)
            BBODY(imsrc + (b * 3 + c) * HW, oim[c * HW] = acc)
        for (int c = ctxBeg; c < c1; c++)
            BBODY(ctxsrc + (b * CTX + (c - 3)) * HW,
                  __builtin_nontemporal_store(acc, &octx[(c - 3) * HW]))
    }
}

// ---------------- launch ----------------

extern "C" void kernel_launch(void* const* d_in, const int* in_sizes, int n_in,
                              void* d_out, int out_size, void* d_ws, size_t ws_size,
                              hipStream_t stream)
{
    const float* im0    = (const float*)d_in[0];
    const float* im2    = (const float*)d_in[1];
    const float* ctx0   = (const float*)d_in[2];
    const float* ctx2   = (const float*)d_in[3];
    const float* flow01 = (const float*)d_in[4];
    const float* flow10 = (const float*)d_in[5];
    const float* dep0   = (const float*)d_in[6];
    const float* dep1   = (const float*)d_in[7];
    const float* filt0  = (const float*)d_in[8];
    const float* filt1  = (const float*)d_in[9];

    float* out = (float*)d_out;

    size_t need = (TSZ + (size_t)2 * BHW) * sizeof(float);
    bool use_t = ws_size >= need;

    float* T   = (float*)d_ws;
    float* cnt = use_t ? ((float*)d_ws + TSZ) : (float*)d_ws;

    hipMemsetAsync(out + OFS_OFF0, 0, (size_t)(4 * BHW) * sizeof(float), stream);
    hipMemsetAsync(cnt, 0, (size_t)(2 * BHW) * sizeof(float), stream);

    dim3 blk(256);
    splat_kernel<<<dim3((2 * BHW + 255) / 256), blk, 0, stream>>>(
        flow01, flow10, dep0, dep1, out, cnt);
    norm_kernel<<<dim3((2 * BHW + 255) / 256), blk, 0, stream>>>(out, cnt);

    if (use_t) {
        transpose_kernel<<<dim3(NTB), blk, 0, stream>>>(im0, im2, ctx0, ctx2, T);
        interp_t_kernel<<<dim3(NBLK2), dim3(NTHR), 0, stream>>>(T, filt0, filt1, out);
    } else {
        dim3 igrid(F_NTILE, F_NGRP, 2);
        interp_f_kernel<<<igrid, blk, 0, stream>>>(
            im0, im2, ctx0, ctx2, filt0, filt1, out);
    }

    cur_kernel<<<dim3((3 * BHW + 255) / 256), blk, 0, stream>>>(out);
}

// Round 10
// 516.975 us; speedup vs baseline: 1.7951x; 1.0517x over previous
//
#include <hip/hip_runtime.h>
#include <hip/hip_fp16.h>
#include <math.h>

#define B   2
#define H   192
#define W   320
#define HW  (H * W)
#define BHW (B * HW)
#define CTX 195
#define CH  198   // 3 im + 195 ctx channels per side

// output offsets (in floats), concatenated in reference return order
#define OFS_CUR   0
#define OFS_REF0  (3 * BHW)
#define OFS_REF2  (6 * BHW)
#define OFS_CTX0  (9 * BHW)
#define OFS_CTX2  (9 * BHW + CTX * BHW)
#define OFS_OFF0  (9 * BHW + 2 * CTX * BHW)
#define OFS_OFF1  (OFS_OFF0 + 2 * BHW)

// transposed-path geometry
#define TSZ    ((size_t)2 * B * HW * CH)  // elements of T (fp16)
#define NTB    (2 * B * (HW / 64))        // 3840 transpose blocks
#define LDSW   199                        // transpose LDS row stride (odd)
#define NPXB   32                         // pixels per interp block
#define NTHR   512                        // interp block threads (8 waves)
#define NCHK   (HW / NPXB)                // 1920 chunks per (s,b) image
#define NBLK2  (2 * B * NCHK)             // 7680 interp blocks, div by 8

// fallback (R4) geometry
#define F_NCH   33
#define F_NGRP  6
#define F_TX    32
#define F_TY    8
#define F_NTX   (W / F_TX)
#define F_NTY   (H / F_TY)
#define F_NTILE (F_NTX * F_NTY * B)       // 480
#define F_NBLK  (F_NTILE * F_NGRP * 2)    // 5760

typedef float f4a __attribute__((ext_vector_type(4), aligned(4)));
typedef _Float16 h4 __attribute__((ext_vector_type(4), aligned(4)));

__device__ __forceinline__ int iclip(int v, int lo, int hi) {
    return v < lo ? lo : (v > hi ? hi : v);
}

// ---------------- splat / norm / cur ----------------

// packed splat: acc4[pix] = {sum(-fx*d), sum(-fy*d), sum(d), pad} -> one cache line
__global__ __launch_bounds__(256) void splat_kernel(
    const float* __restrict__ flow0, const float* __restrict__ flow1,
    const float* __restrict__ dep0,  const float* __restrict__ dep1,
    float* __restrict__ acc4)
{
    int tid = blockIdx.x * blockDim.x + threadIdx.x;
    if (tid >= 2 * BHW) return;
    int s   = tid / BHW;
    int p   = tid - s * BHW;
    int b   = p / HW;
    int pix = p - b * HW;
    int y   = pix / W;
    int x   = pix - y * W;

    const float* flow = s ? flow1 : flow0;
    const float* dep  = s ? dep1  : dep0;
    float fx = flow[(b * 2 + 0) * HW + pix];
    float fy = flow[(b * 2 + 1) * HW + pix];
    float d  = dep[b * HW + pix];

    int xL = (int)floorf((float)x + fx);
    int yT = (int)floorf((float)y + fy);

    float* ab = acc4 + (size_t)(s * B + b) * HW * 4;

    float wx = -fx * d;
    float wy = -fy * d;
    #pragma unroll
    for (int dy = 0; dy < 2; dy++) {
        #pragma unroll
        for (int dx = 0; dx < 2; dx++) {
            int xi = xL + dx;
            int yi = yT + dy;
            if (xi >= 0 && xi < W && yi >= 0 && yi < H) {
                float* q = ab + (size_t)(yi * W + xi) * 4;
                atomicAdd(q + 0, wx);
                atomicAdd(q + 1, wy);
                atomicAdd(q + 2, d);
            }
        }
    }
}

// off = acc/cnt if cnt>0 else 0; writes EVERY pixel (no memset of out needed)
__global__ __launch_bounds__(256) void norm_kernel(
    float* __restrict__ out, const float* __restrict__ acc4)
{
    int tid = blockIdx.x * blockDim.x + threadIdx.x;
    if (tid >= 2 * BHW) return;
    int s   = tid / BHW;
    int p   = tid - s * BHW;
    int b   = p / HW;
    int pix = p - b * HW;

    const float* q = acc4 + ((size_t)(s * B + b) * HW + pix) * 4;
    float ax = q[0], ay = q[1], c = q[2];
    float* acc = out + (s ? OFS_OFF1 : OFS_OFF0) + b * 2 * HW;
    if (c > 0.0f) {
        acc[pix]      = ax / c;
        acc[HW + pix] = ay / c;
    } else {
        acc[pix]      = 0.0f;
        acc[HW + pix] = 0.0f;
    }
}

__global__ __launch_bounds__(256) void cur_kernel(float* __restrict__ out)
{
    int i = blockIdx.x * blockDim.x + threadIdx.x;
    if (i < 3 * BHW)
        out[OFS_CUR + i] = 0.5f * (out[OFS_REF0 + i] + out[OFS_REF2 + i]);
}

// ---------------- transposed path ----------------

// T[((s*B+b)*HW + pix)*CH + c] = (fp16) plane_c[pix]; coalesced via LDS.
__global__ __launch_bounds__(256) void transpose_kernel(
    const float* __restrict__ im0,  const float* __restrict__ im2,
    const float* __restrict__ ctx0, const float* __restrict__ ctx2,
    _Float16* __restrict__ T)
{
    __shared__ float lds[64 * LDSW];
    int lin   = blockIdx.x;
    int chunk = lin % (HW / 64);
    int rest  = lin / (HW / 64);
    int b = rest % B;
    int s = rest / B;
    int pix0 = chunk * 64;

    const float* im  = s ? im2  : im0;
    const float* ctx = s ? ctx2 : ctx0;

    for (int j = (int)threadIdx.x; j < CH * 64; j += 256) {
        int c = j >> 6;
        int p = j & 63;
        const float* src = (c < 3) ? im + (b * 3 + c) * HW
                                   : ctx + (b * CTX + (c - 3)) * HW;
        lds[p * LDSW + c] = src[pix0 + p];
    }
    __syncthreads();
    _Float16* Tb = T + ((size_t)((s * B + b) * HW + pix0)) * CH;
    for (int j = (int)threadIdx.x; j < CH * 64; j += 256) {
        int p = j / CH;
        int c = j - p * CH;
        Tb[(size_t)p * CH + c] = (_Float16)lds[p * LDSW + c];
    }
}

// 8 waves x 4 px each; lanes = channel quads (c = 4*lane, 50 active), fp16 T.
__global__ __launch_bounds__(NTHR) void interp_t_kernel(
    const _Float16* __restrict__ T,
    const float* __restrict__ filt0, const float* __restrict__ filt1,
    float* __restrict__ out)
{
    __shared__ float fwl[NPXB * 17];    // [p][tap], stride 17
    __shared__ float mwl[NPXB * 25];    // [p][r*5+c]
    __shared__ float geof[NPXB * 6];    // a00,a10,a01,a11
    __shared__ int   geoi[NPXB * 4];    // flag(0 inv,1 int,2 bord), xL, yT
    __shared__ float outb[NPXB * 199];  // [p][c], stride 199 (odd)

    int lin = blockIdx.x;
    int newlin = (lin & 7) * (NBLK2 / 8) + (lin >> 3);   // XCD swizzle
    int chunk = newlin % NCHK;
    int rest  = newlin / NCHK;
    int b = rest % B;
    int s = rest / B;
    int px0 = chunk * NPXB;      // 32 consecutive px within one row
    int y0  = px0 / W;
    int x0  = px0 - y0 * W;

    const float* off  = out + (s ? OFS_OFF1 : OFS_OFF0) + b * 2 * HW;
    const float* filt = (s ? filt1 : filt0) + b * 16 * HW;
    const _Float16* Tb = T + (size_t)(s * B + b) * HW * CH;

    int t = (int)threadIdx.x;

    for (int idx = t; idx < 16 * NPXB; idx += NTHR) {
        int tap = idx >> 5, p = idx & 31;
        fwl[p * 17 + tap] = filt[tap * HW + px0 + p];
    }
    if (t < NPXB) {
        int p = t;
        float ox = off[px0 + p];
        float oy = off[HW + px0 + p];
        float x2 = (float)(x0 + p) + ox;
        float y2 = (float)y0 + oy;
        bool valid = (x2 >= 0.0f) && (x2 <= (float)(W - 1)) &&
                     (y2 >= 0.0f) && (y2 <= (float)(H - 1));
        float xLf = floorf(x2), yTf = floorf(y2);
        float al = x2 - xLf, be = y2 - yTf;
        int xL = (int)xLf, yT = (int)yTf;
        bool interior = valid && (xL >= 1) && (xL <= W - 4) &&
                                 (yT >= 1) && (yT <= H - 4);
        geof[p * 6 + 0] = valid ? (1.0f - al) * (1.0f - be) : 0.0f;
        geof[p * 6 + 1] = valid ? al * (1.0f - be) : 0.0f;
        geof[p * 6 + 2] = valid ? (1.0f - al) * be : 0.0f;
        geof[p * 6 + 3] = valid ? al * be : 0.0f;
        geoi[p * 4 + 0] = valid ? (interior ? 1 : 2) : 0;
        geoi[p * 4 + 1] = xL;
        geoi[p * 4 + 2] = yT;
    }
    __syncthreads();
    for (int idx = t; idx < 25 * NPXB; idx += NTHR) {
        int p = idx / 25, rc = idx - p * 25;
        int r = rc / 5, c = rc - r * 5;
        float a00 = geof[p * 6 + 0], a10 = geof[p * 6 + 1];
        float a01 = geof[p * 6 + 2], a11 = geof[p * 6 + 3];
        const float* fw = &fwl[p * 17];
        float v = 0.0f;
        if (r < 4 && c < 4)   v += a00 * fw[r * 4 + c];
        if (r < 4 && c >= 1)  v += a10 * fw[r * 4 + c - 1];
        if (r >= 1 && c < 4)  v += a01 * fw[(r - 1) * 4 + c];
        if (r >= 1 && c >= 1) v += a11 * fw[(r - 1) * 4 + c - 1];
        mwl[p * 25 + rc] = v;
    }
    __syncthreads();

    int wave = t >> 6, lane = t & 63;
    int lcl = lane < 49 ? lane : 49;
    int cc0 = 4 * lcl;                       // channels cc0..cc0+3
    int nwr = lane < 49 ? 4 : (lane == 49 ? 2 : 0);

    #pragma unroll
    for (int pi = 0; pi < 4; pi++) {
        int p = wave * 4 + pi;
        int flag = geoi[p * 4];
        float acc0 = 0.0f, acc1 = 0.0f, acc2 = 0.0f, acc3 = 0.0f;
        if (flag == 1) {
            int xL = geoi[p * 4 + 1], yT = geoi[p * 4 + 2];
            const _Float16* basep =
                Tb + ((size_t)(yT - 1) * W + (xL - 1)) * CH + cc0;
            #pragma unroll
            for (int r = 0; r < 5; r++) {
                #pragma unroll
                for (int cc = 0; cc < 5; cc++) {
                    h4 v = *(const h4*)(basep + ((size_t)r * W + cc) * CH);
                    float wgt = mwl[p * 25 + r * 5 + cc];
                    acc0 = fmaf(wgt, (float)v.x, acc0);
                    acc1 = fmaf(wgt, (float)v.y, acc1);
                    acc2 = fmaf(wgt, (float)v.z, acc2);
                    acc3 = fmaf(wgt, (float)v.w, acc3);
                }
            }
        } else if (flag == 2) {
            int xL = geoi[p * 4 + 1], yT = geoi[p * 4 + 2];
            float a00 = geof[p * 6 + 0], a10 = geof[p * 6 + 1];
            float a01 = geof[p * 6 + 2], a11 = geof[p * 6 + 3];
            int xi[4], xi1[4], yi[4], yi1[4];
            #pragma unroll
            for (int f = 0; f < 4; f++) {
                int a = iclip(xL + f - 1, 0, W - 1);
                xi[f]  = a;
                xi1[f] = a + 1 > W - 1 ? W - 1 : a + 1;
                int bb = iclip(yT + f - 1, 0, H - 1);
                yi[f]  = bb;
                yi1[f] = bb + 1 > H - 1 ? H - 1 : bb + 1;
            }
            #pragma unroll
            for (int fj = 0; fj < 4; fj++) {
                #pragma unroll
                for (int fi = 0; fi < 4; fi++) {
                    const _Float16* ptl = Tb + ((size_t)yi[fj]  * W + xi[fi])  * CH + cc0;
                    const _Float16* ptr_ = Tb + ((size_t)yi[fj]  * W + xi1[fi]) * CH + cc0;
                    const _Float16* pbl = Tb + ((size_t)yi1[fj] * W + xi[fi])  * CH + cc0;
                    const _Float16* pbr = Tb + ((size_t)yi1[fj] * W + xi1[fi]) * CH + cc0;
                    h4 tl = *(const h4*)ptl;
                    h4 tr = *(const h4*)ptr_;
                    h4 bl = *(const h4*)pbl;
                    h4 br = *(const h4*)pbr;
                    float wgt = fwl[p * 17 + fj * 4 + fi];
                    acc0 = fmaf(wgt, a00*(float)tl.x + a10*(float)tr.x + a01*(float)bl.x + a11*(float)br.x, acc0);
                    acc1 = fmaf(wgt, a00*(float)tl.y + a10*(float)tr.y + a01*(float)bl.y + a11*(float)br.y, acc1);
                    acc2 = fmaf(wgt, a00*(float)tl.z + a10*(float)tr.z + a01*(float)bl.z + a11*(float)br.z, acc2);
                    acc3 = fmaf(wgt, a00*(float)tl.w + a10*(float)tr.w + a01*(float)bl.w + a11*(float)br.w, acc3);
                }
            }
        }
        float* ob = &outb[p * 199 + cc0];
        if (nwr == 4) { ob[0] = acc0; ob[1] = acc1; ob[2] = acc2; ob[3] = acc3; }
        else if (nwr == 2) { ob[0] = acc0; ob[1] = acc1; }
    }

    __syncthreads();
    for (int idx = t; idx < CH * NPXB; idx += NTHR) {
        int c = idx >> 5;
        int p = idx & 31;
        float v = outb[p * 199 + c];
        if (c < 3)
            out[(s ? OFS_REF2 : OFS_REF0) + (b * 3 + c) * HW + px0 + p] = v;
        else
            __builtin_nontemporal_store(
                v, &out[(s ? OFS_CTX2 : OFS_CTX0) + (b * CTX + (c - 3)) * HW + px0 + p]);
    }
}

// ---------------- fallback path (R4 interp, fp32 planes) ----------------

#define VBODY(PLANE, STORE)                                            \
    {                                                                  \
        const float* p0 = (PLANE) + base;                              \
        float acc = 0.0f;                                              \
        _Pragma("unroll")                                              \
        for (int r = 0; r < 5; r++) {                                  \
            const float* row = p0 + r * W;                             \
            f4a v0 = *(const f4a*)row;                                 \
            float v4 = row[4];                                         \
            acc = fmaf(mw[r][0], v0.x, acc);                           \
            acc = fmaf(mw[r][1], v0.y, acc);                           \
            acc = fmaf(mw[r][2], v0.z, acc);                           \
            acc = fmaf(mw[r][3], v0.w, acc);                           \
            acc = fmaf(mw[r][4], v4,   acc);                           \
        }                                                              \
        STORE;                                                         \
    }

#define BBODY(PLANE, STORE)                                            \
    {                                                                  \
        const float* plane = (PLANE);                                  \
        float acc = 0.0f;                                              \
        _Pragma("unroll")                                              \
        for (int fj = 0; fj < 4; fj++) {                               \
            const float* rT = plane + yi[fj]  * W;                     \
            const float* rB = plane + yi1[fj] * W;                     \
            _Pragma("unroll")                                          \
            for (int fi = 0; fi < 4; fi++) {                           \
                float samp = a00 * rT[xi[fi]] + a10 * rT[xi1[fi]]      \
                           + a01 * rB[xi[fi]] + a11 * rB[xi1[fi]];     \
                acc = fmaf(fw[fj * 4 + fi], samp, acc);                \
            }                                                          \
        }                                                              \
        STORE;                                                         \
    }

__global__ __launch_bounds__(256) void interp_f_kernel(
    const float* __restrict__ im0,   const float* __restrict__ im2,
    const float* __restrict__ ctx0,  const float* __restrict__ ctx2,
    const float* __restrict__ filt0, const float* __restrict__ filt1,
    float* __restrict__ out)
{
    int lin = blockIdx.x + F_NTILE * (blockIdx.y + F_NGRP * blockIdx.z);
    int newlin = (lin & 7) * (F_NBLK / 8) + (lin >> 3);
    int tile = newlin % F_NTILE;
    int rest = newlin / F_NTILE;
    int g = rest % F_NGRP;
    int s = rest / F_NGRP;
    int b  = tile / (F_NTX * F_NTY);
    int t2 = tile % (F_NTX * F_NTY);
    int x = (t2 % F_NTX) * F_TX + ((int)threadIdx.x % F_TX);
    int y = (t2 / F_NTX) * F_TY + ((int)threadIdx.x / F_TX);
    int pix = y * W + x;

    const float* off = out + (s ? OFS_OFF1 : OFS_OFF0) + b * 2 * HW;
    float ox = off[pix];
    float oy = off[HW + pix];
    float x2 = (float)x + ox;
    float y2 = (float)y + oy;

    bool valid = (x2 >= 0.0f) && (x2 <= (float)(W - 1)) &&
                 (y2 >= 0.0f) && (y2 <= (float)(H - 1));

    const float* imsrc  = s ? im2  : im0;
    const float* ctxsrc = s ? ctx2 : ctx0;
    float* oim  = out + (s ? OFS_REF2 : OFS_REF0) + b * 3 * HW + pix;
    float* octx = out + (s ? OFS_CTX2 : OFS_CTX0) + b * CTX * HW + pix;

    int c0 = g * F_NCH, c1 = c0 + F_NCH;
    int imEnd  = c1 < 3 ? c1 : 3;
    int ctxBeg = c0 > 3 ? c0 : 3;

    if (!valid) {
        for (int c = c0; c < imEnd; c++) oim[c * HW] = 0.0f;
        for (int c = ctxBeg; c < c1; c++)
            __builtin_nontemporal_store(0.0f, &octx[(c - 3) * HW]);
        return;
    }

    float xLf = floorf(x2), yTf = floorf(y2);
    float alpha = x2 - xLf, beta = y2 - yTf;
    int xL = (int)xLf, yT = (int)yTf;

    const float* filt = (s ? filt1 : filt0) + b * 16 * HW + pix;
    float fw[16];
    #pragma unroll
    for (int t = 0; t < 16; t++) fw[t] = filt[t * HW];

    float a00 = (1.0f - alpha) * (1.0f - beta);
    float a10 = alpha * (1.0f - beta);
    float a01 = (1.0f - alpha) * beta;
    float a11 = alpha * beta;

    bool interior = (xL >= 1) && (xL <= W - 4) && (yT >= 1) && (yT <= H - 4);

    if (interior) {
        float mw[5][5];
        #pragma unroll
        for (int r = 0; r < 5; r++) {
            #pragma unroll
            for (int c = 0; c < 5; c++) {
                float v = 0.0f;
                if (r < 4 && c < 4)   v += a00 * fw[r * 4 + c];
                if (r < 4 && c >= 1)  v += a10 * fw[r * 4 + c - 1];
                if (r >= 1 && c < 4)  v += a01 * fw[(r - 1) * 4 + c];
                if (r >= 1 && c >= 1) v += a11 * fw[(r - 1) * 4 + c - 1];
                mw[r][c] = v;
            }
        }
        int base = (yT - 1) * W + (xL - 1);
        for (int c = c0; c < imEnd; c++)
            VBODY(imsrc + (b * 3 + c) * HW, oim[c * HW] = acc)
        #pragma unroll 2
        for (int c = ctxBeg; c < c1; c++)
            VBODY(ctxsrc + (b * CTX + (c - 3)) * HW,
                  __builtin_nontemporal_store(acc, &octx[(c - 3) * HW]))
    } else {
        int xi[4], xi1[4], yi[4], yi1[4];
        #pragma unroll
        for (int f = 0; f < 4; f++) {
            int a = iclip(xL + f - 1, 0, W - 1);
            xi[f]  = a;
            xi1[f] = a + 1 > W - 1 ? W - 1 : a + 1;
            int bb = iclip(yT + f - 1, 0, H - 1);
            yi[f]  = bb;
            yi1[f] = bb + 1 > H - 1 ? H - 1 : bb + 1;
        }
        for (int c = c0; c < imEnd; c++)
            BBODY(imsrc + (b * 3 + c) * HW, oim[c * HW] = acc)
        for (int c = ctxBeg; c < c1; c++)
            BBODY(ctxsrc + (b * CTX + (c - 3)) * HW,
                  __builtin_nontemporal_store(acc, &octx[(c - 3) * HW]))
    }
}

// ---------------- launch ----------------

extern "C" void kernel_launch(void* const* d_in, const int* in_sizes, int n_in,
                              void* d_out, int out_size, void* d_ws, size_t ws_size,
                              hipStream_t stream)
{
    const float* im0    = (const float*)d_in[0];
    const float* im2    = (const float*)d_in[1];
    const float* ctx0   = (const float*)d_in[2];
    const float* ctx2   = (const float*)d_in[3];
    const float* flow01 = (const float*)d_in[4];
    const float* flow10 = (const float*)d_in[5];
    const float* dep0   = (const float*)d_in[6];
    const float* dep1   = (const float*)d_in[7];
    const float* filt0  = (const float*)d_in[8];
    const float* filt1  = (const float*)d_in[9];

    float* out = (float*)d_out;

    // ws layout: acc4 (2*BHW*4 floats) | T (TSZ halfs)
    size_t acc4_bytes = (size_t)2 * BHW * 4 * sizeof(float);
    size_t need = acc4_bytes + TSZ * sizeof(_Float16);
    bool use_t = ws_size >= need;

    float* acc4 = (float*)d_ws;
    _Float16* T = (_Float16*)((char*)d_ws + acc4_bytes);

    hipMemsetAsync(acc4, 0, acc4_bytes, stream);

    dim3 blk(256);
    splat_kernel<<<dim3((2 * BHW + 255) / 256), blk, 0, stream>>>(
        flow01, flow10, dep0, dep1, acc4);
    norm_kernel<<<dim3((2 * BHW + 255) / 256), blk, 0, stream>>>(out, acc4);

    if (use_t) {
        transpose_kernel<<<dim3(NTB), blk, 0, stream>>>(im0, im2, ctx0, ctx2, T);
        interp_t_kernel<<<dim3(NBLK2), dim3(NTHR), 0, stream>>>(T, filt0, filt1, out);
    } else {
        dim3 igrid(F_NTILE, F_NGRP, 2);
        interp_f_kernel<<<igrid, blk, 0, stream>>>(
            im0, im2, ctx0, ctx2, filt0, filt1, out);
    }

    cur_kernel<<<dim3((3 * BHW + 255) / 256), blk, 0, stream>>>(out);
}